// Round 1
// baseline (982.244 us; speedup 1.0000x reference)
//
#include <hip/hip_runtime.h>

#define IDIM 512
#define MIXD 32
#define HID 96
#define BB 256
#define TT 512

__device__ __forceinline__ float sigm(float x) {
    return __builtin_amdgcn_rcpf(1.f + __expf(-x));
}
__device__ __forceinline__ float tanh_fast(float x) {
    // 1 - 2/(1+e^{2x}); saturates correctly at +-1 for large |x|
    return 1.f - 2.f * __builtin_amdgcn_rcpf(1.f + __expf(2.f * x));
}

// ---------------- K1: z = x @ W_mix^T  (memory-bound, 268 MB read) ----------
// grid 512 x 256: one row (b,t) per thread; W reads are wave-uniform -> s_load
__global__ __launch_bounds__(256) void k_mix(const float* __restrict__ x,
                                             const float* __restrict__ Wmix,
                                             float* __restrict__ z) {
    long row = (long)blockIdx.x * 256 + threadIdx.x;   // 131072 rows
    const float* xr = x + row * IDIM;
    float acc[MIXD];
    #pragma unroll
    for (int m = 0; m < MIXD; ++m) acc[m] = 0.f;
    for (int kc = 0; kc < IDIM / 4; ++kc) {
        float4 a = *(const float4*)(xr + kc * 4);
        #pragma unroll
        for (int m = 0; m < MIXD; ++m) {
            float4 w = *(const float4*)(Wmix + m * IDIM + kc * 4); // uniform
            acc[m] += a.x * w.x + a.y * w.y + a.z * w.z + a.w * w.w;
        }
    }
    float* zr = z + row * MIXD;
    #pragma unroll
    for (int mc = 0; mc < MIXD / 4; ++mc) {
        float4 o;
        o.x = acc[mc*4+0]; o.y = acc[mc*4+1]; o.z = acc[mc*4+2]; o.w = acc[mc*4+3];
        *(float4*)(zr + mc * 4) = o;
    }
}

// ---------------- K2: sequential GRU scan, 1 batch element per block --------
// 256 threads = 4 waves; wave w owns gates [72w, 72w+64) fully, gates
// [72w+64, 72w+72) are k-split 8 ways across lanes (12 hh-MACs + 4 ih-MACs
// each) and reduced with shfl_xor. Weights live in registers; h, z, and gate
// exchange go through (tiny) LDS. z is prefetched 2..4 steps ahead.
__global__ __launch_bounds__(256) void k_scan(const float* __restrict__ z,
                                              const float* __restrict__ Wih,
                                              const float* __restrict__ Whh,
                                              const float* __restrict__ bih,
                                              const float* __restrict__ bhh,
                                              float* __restrict__ hout) {
    const int b   = blockIdx.x;
    const int tid = threadIdx.x;
    const int w   = tid >> 6, l = tid & 63;
    const int s   = l & 7,   i = l >> 3;
    const int go  = 72 * w + l;        // own gate, < 288 always
    const int ge  = 72 * w + 64 + i;   // extra (remainder) gate

    __shared__ __align__(16) float sh[HID];
    __shared__ __align__(16) float sr[HID];
    __shared__ __align__(16) float su[HID];
    __shared__ __align__(16) float sn[HID];
    __shared__ __align__(16) float sz[4][MIXD];

    // ---- load weights into registers (fully unrolled -> static indexing) ----
    float wh[HID], wi[MIXD];
    #pragma unroll
    for (int kc = 0; kc < HID / 4; ++kc) {
        float4 v = *(const float4*)(Whh + go * HID + kc * 4);
        wh[kc*4+0]=v.x; wh[kc*4+1]=v.y; wh[kc*4+2]=v.z; wh[kc*4+3]=v.w;
    }
    #pragma unroll
    for (int mc = 0; mc < MIXD / 4; ++mc) {
        float4 v = *(const float4*)(Wih + go * MIXD + mc * 4);
        wi[mc*4+0]=v.x; wi[mc*4+1]=v.y; wi[mc*4+2]=v.z; wi[mc*4+3]=v.w;
    }
    const float bi = bih[go], bh = bhh[go];

    float whe[12], wie[4];
    #pragma unroll
    for (int c = 0; c < 3; ++c) {
        float4 v = *(const float4*)(Whh + ge * HID + s * 12 + c * 4);
        whe[c*4+0]=v.x; whe[c*4+1]=v.y; whe[c*4+2]=v.z; whe[c*4+3]=v.w;
    }
    {
        float4 v = *(const float4*)(Wih + ge * MIXD + s * 4);
        wie[0]=v.x; wie[1]=v.y; wie[2]=v.z; wie[3]=v.w;
    }
    const float bie = bih[ge], bhe = bhh[ge];

    // ---- prologue: z ring prefetch + h0 = 0 ----
    const float* zb = z + (long)b * TT * MIXD;
    float zp0 = 0.f, zp1 = 0.f;
    if (tid < MIXD) {
        sz[0][tid] = zb[0 * MIXD + tid];
        sz[1][tid] = zb[1 * MIXD + tid];
        zp0 = zb[2 * MIXD + tid];
        zp1 = zb[3 * MIXD + tid];
    }
    if (tid < HID) sh[tid] = 0.f;
    __syncthreads();

    #pragma unroll 1
    for (int t = 0; t < TT; ++t) {
        // A: stage z[t+2] (loaded 2 steps ago), issue load for z[t+4]
        if (tid < MIXD) {
            if (t + 2 < TT) sz[(t + 2) & 3][tid] = zp0;
            zp0 = zp1;
            if (t + 4 < TT) zp1 = zb[(t + 4) * MIXD + tid];
        }
        const float* zz = sz[t & 3];

        // B: own-gate dots (gx = W_ih z + b_ih ; gh = W_hh h + b_hh)
        float a0 = bi, a1 = 0.f, a2 = 0.f, a3 = 0.f;
        #pragma unroll
        for (int mc = 0; mc < MIXD / 4; ++mc) {
            float4 v = *(const float4*)(zz + mc * 4);
            a0 += wi[mc*4+0]*v.x; a1 += wi[mc*4+1]*v.y;
            a2 += wi[mc*4+2]*v.z; a3 += wi[mc*4+3]*v.w;
        }
        const float gx = (a0 + a1) + (a2 + a3);
        float c0 = bh, c1 = 0.f, c2 = 0.f, c3 = 0.f;
        #pragma unroll
        for (int kc = 0; kc < HID / 4; ++kc) {
            float4 v = *(const float4*)(sh + kc * 4);
            c0 += wh[kc*4+0]*v.x; c1 += wh[kc*4+1]*v.y;
            c2 += wh[kc*4+2]*v.z; c3 += wh[kc*4+3]*v.w;
        }
        const float gh = (c0 + c1) + (c2 + c3);

        // C: remainder-gate k-slice partials + butterfly reduce over 8 lanes
        float pgx, pgh;
        {
            float4 v = *(const float4*)(zz + s * 4);
            pgx = wie[0]*v.x + wie[1]*v.y + wie[2]*v.z + wie[3]*v.w;
        }
        {
            float e0 = 0.f, e1 = 0.f, e2 = 0.f, e3 = 0.f;
            #pragma unroll
            for (int c = 0; c < 3; ++c) {
                float4 v = *(const float4*)(sh + s * 12 + c * 4);
                e0 += whe[c*4+0]*v.x; e1 += whe[c*4+1]*v.y;
                e2 += whe[c*4+2]*v.z; e3 += whe[c*4+3]*v.w;
            }
            pgh = (e0 + e1) + (e2 + e3);
        }
        pgx += __shfl_xor(pgx, 1); pgx += __shfl_xor(pgx, 2); pgx += __shfl_xor(pgx, 4);
        pgh += __shfl_xor(pgh, 1); pgh += __shfl_xor(pgh, 2); pgh += __shfl_xor(pgh, 4);

        // D/E: r,u activations before barrier; n pre-acts kept in registers
        float ngx = 0.f, ngh = 0.f, engx = 0.f, engh = 0.f;
        if (go < HID)            sr[go]        = sigm(gx + gh);
        else if (go < 2 * HID)   su[go - HID]  = sigm(gx + gh);
        else                     { ngx = gx; ngh = gh; }
        if (s == 0) {
            float egx = pgx + bie, egh = pgh + bhe;
            if (ge < HID)          sr[ge]       = sigm(egx + egh);
            else if (ge < 2*HID)   su[ge - HID] = sigm(egx + egh);
            else                   { engx = egx; engh = egh; }
        }
        __syncthreads();

        // F: n = tanh(xn + r * hn)
        if (go >= 2 * HID) {
            int j = go - 2 * HID;
            sn[j] = tanh_fast(ngx + sr[j] * ngh);
        }
        if (s == 0 && ge >= 2 * HID) {
            int j = ge - 2 * HID;
            sn[j] = tanh_fast(engx + sr[j] * engh);
        }
        __syncthreads();

        // G: h = (1-u)*n + u*h
        if (tid < HID) {
            float u = su[tid];
            sh[tid] = (1.f - u) * sn[tid] + u * sh[tid];
        }
        __syncthreads();
    }

    if (tid < HID) hout[b * HID + tid] = sh[tid];
}

// ---------------- K3: y = (W_head h + b_head) @ W_mix -----------------------
__global__ __launch_bounds__(256) void k_head(const float* __restrict__ hlast,
                                              const float* __restrict__ Whead,
                                              const float* __restrict__ bhead,
                                              const float* __restrict__ Wmix,
                                              float* __restrict__ y) {
    __shared__ __align__(16) float sh[HID];
    __shared__ __align__(16) float szn[MIXD];
    const int b = blockIdx.x, tid = threadIdx.x;
    if (tid < HID) sh[tid] = hlast[b * HID + tid];
    __syncthreads();
    if (tid < MIXD) {
        float a0 = 0.f, a1 = 0.f, a2 = 0.f, a3 = 0.f;
        #pragma unroll
        for (int kc = 0; kc < HID / 4; ++kc) {
            float4 hv = *(const float4*)(sh + kc * 4);
            float4 wv = *(const float4*)(Whead + tid * HID + kc * 4);
            a0 += wv.x*hv.x; a1 += wv.y*hv.y; a2 += wv.z*hv.z; a3 += wv.w*hv.w;
        }
        szn[tid] = bhead[tid] + ((a0 + a1) + (a2 + a3));
    }
    __syncthreads();
    #pragma unroll
    for (int rep = 0; rep < 2; ++rep) {
        int j = tid + rep * 256;
        float acc = 0.f;
        #pragma unroll
        for (int m = 0; m < MIXD; ++m)
            acc += szn[m] * Wmix[m * IDIM + j];
        y[(long)b * IDIM + j] = acc;
    }
}

extern "C" void kernel_launch(void* const* d_in, const int* in_sizes, int n_in,
                              void* d_out, int out_size, void* d_ws, size_t ws_size,
                              hipStream_t stream) {
    const float* x     = (const float*)d_in[0];
    const float* Wmix  = (const float*)d_in[1];
    const float* Wih   = (const float*)d_in[2];
    const float* Whh   = (const float*)d_in[3];
    const float* bih   = (const float*)d_in[4];
    const float* bhh   = (const float*)d_in[5];
    const float* Whead = (const float*)d_in[6];
    const float* bhead = (const float*)d_in[7];
    float* out = (float*)d_out;

    float* z     = (float*)d_ws;                       // [B*T, 32] = 16.78 MB
    float* hlast = z + (size_t)BB * TT * MIXD;         // [B, 96]

    k_mix <<<512, 256, 0, stream>>>(x, Wmix, z);
    k_scan<<<BB,  256, 0, stream>>>(z, Wih, Whh, bih, bhh, hlast);
    k_head<<<BB,  256, 0, stream>>>(hlast, Whead, bhead, Wmix, out);
}

// Round 2
// 546.583 us; speedup vs baseline: 1.7971x; 1.7971x over previous
//
#include <hip/hip_runtime.h>

#define IDIM 512
#define MIXD 32
#define HID 96
#define BB 256
#define TT 512

__device__ __forceinline__ float sigm(float x) {
    return __builtin_amdgcn_rcpf(1.f + __expf(-x));
}
__device__ __forceinline__ float tanh_fast(float x) {
    // 1 - 2/(1+e^{2x}); saturates correctly at +-1 for large |x|
    return 1.f - 2.f * __builtin_amdgcn_rcpf(1.f + __expf(2.f * x));
}

// ---------------- K1: z = x @ W_mix^T  (memory-bound, 268 MB read) ----------
__global__ __launch_bounds__(256) void k_mix(const float* __restrict__ x,
                                             const float* __restrict__ Wmix,
                                             float* __restrict__ z) {
    long row = (long)blockIdx.x * 256 + threadIdx.x;   // 131072 rows
    const float* xr = x + row * IDIM;
    float acc[MIXD];
    #pragma unroll
    for (int m = 0; m < MIXD; ++m) acc[m] = 0.f;
    for (int kc = 0; kc < IDIM / 4; ++kc) {
        float4 a = *(const float4*)(xr + kc * 4);
        #pragma unroll
        for (int m = 0; m < MIXD; ++m) {
            float4 w = *(const float4*)(Wmix + m * IDIM + kc * 4); // uniform -> s_load
            acc[m] += a.x * w.x + a.y * w.y + a.z * w.z + a.w * w.w;
        }
    }
    float* zr = z + row * MIXD;
    #pragma unroll
    for (int mc = 0; mc < MIXD / 4; ++mc) {
        float4 o;
        o.x = acc[mc*4+0]; o.y = acc[mc*4+1]; o.z = acc[mc*4+2]; o.w = acc[mc*4+3];
        *(float4*)(zr + mc * 4) = o;
    }
}

// ---------------- K2: GRU scan + head, 1 batch element per block ------------
// 768 threads = 12 waves (3/SIMD). h-index j = tid>>3 (0..95), octet lane
// o = tid&7. Each octet computes ALL THREE gates (r,u,n) for its j with an
// 8-way k-split (12 hh-MACs + 4 ih-MACs per gate per lane) reduced by a
// 3-level shfl_xor tree. No r/u/n exchange through LDS; h is ping-pong
// double-buffered in LDS -> exactly ONE barrier per step. z is staged into
// LDS in 32 KB half-chunks, so the step loop has ZERO global memory ops
// (no vmcnt drain at the barrier).
__global__ __launch_bounds__(768) void k_scan(const float* __restrict__ z,
                                              const float* __restrict__ Wih,
                                              const float* __restrict__ Whh,
                                              const float* __restrict__ bih,
                                              const float* __restrict__ bhh,
                                              const float* __restrict__ Whead,
                                              const float* __restrict__ bhead,
                                              const float* __restrict__ Wmix,
                                              float* __restrict__ y) {
    const int b   = blockIdx.x;
    const int tid = threadIdx.x;
    const int j   = tid >> 3;     // 0..95
    const int o   = tid & 7;      // 0..7

    __shared__ __align__(16) float sz[256 * MIXD];   // 32 KB: half of the z row
    __shared__ __align__(16) float shp[2][HID];      // h ping-pong
    __shared__ __align__(16) float szn[MIXD];

    // ---- weights into registers (k-slice of rows j, j+96, j+192) ----
    float whr[12], whu[12], whn[12];
    #pragma unroll
    for (int c = 0; c < 3; ++c) {
        float4 v = *(const float4*)(Whh + (size_t)(j        ) * HID + o * 12 + c * 4);
        whr[c*4+0]=v.x; whr[c*4+1]=v.y; whr[c*4+2]=v.z; whr[c*4+3]=v.w;
    }
    #pragma unroll
    for (int c = 0; c < 3; ++c) {
        float4 v = *(const float4*)(Whh + (size_t)(j +   HID) * HID + o * 12 + c * 4);
        whu[c*4+0]=v.x; whu[c*4+1]=v.y; whu[c*4+2]=v.z; whu[c*4+3]=v.w;
    }
    #pragma unroll
    for (int c = 0; c < 3; ++c) {
        float4 v = *(const float4*)(Whh + (size_t)(j + 2*HID) * HID + o * 12 + c * 4);
        whn[c*4+0]=v.x; whn[c*4+1]=v.y; whn[c*4+2]=v.z; whn[c*4+3]=v.w;
    }
    float wir[4], wiu[4], win[4];
    {
        float4 v = *(const float4*)(Wih + (size_t)(j        ) * MIXD + o * 4);
        wir[0]=v.x; wir[1]=v.y; wir[2]=v.z; wir[3]=v.w;
    }
    {
        float4 v = *(const float4*)(Wih + (size_t)(j +   HID) * MIXD + o * 4);
        wiu[0]=v.x; wiu[1]=v.y; wiu[2]=v.z; wiu[3]=v.w;
    }
    {
        float4 v = *(const float4*)(Wih + (size_t)(j + 2*HID) * MIXD + o * 4);
        win[0]=v.x; win[1]=v.y; win[2]=v.z; win[3]=v.w;
    }
    float br = 0.f, bu = 0.f, bxn = 0.f, bhn = 0.f;
    if (o == 0) {
        br  = bih[j]       + bhh[j];
        bu  = bih[j + HID] + bhh[j + HID];
        bxn = bih[j + 2*HID];
        bhn = bhh[j + 2*HID];
    }

    if (tid < HID) shp[0][tid] = 0.f;   // h0 = 0 (covered by stage barrier)

    const float4* zb4 = (const float4*)(z + (size_t)b * TT * MIXD);
    float4* sz4 = (float4*)sz;

    for (int c = 0; c < TT / 256; ++c) {
        // stage 256 steps of z (2048 float4); prior step's barrier makes
        // overwrite safe, next barrier makes it visible
        for (int idx = tid; idx < 2048; idx += 768)
            sz4[idx] = zb4[c * 2048 + idx];
        __syncthreads();

        for (int tt = 0; tt < 256; ++tt) {
            const int t = (c << 8) + tt;
            const float* hr = shp[t & 1];
            float*       hw = shp[(t + 1) & 1];
            const float* zrow = sz + tt * MIXD;

            float4 z4 = *(const float4*)(zrow + o * 4);
            float hh[12];
            {
                float4 h0 = *(const float4*)(hr + o * 12);
                float4 h1 = *(const float4*)(hr + o * 12 + 4);
                float4 h2 = *(const float4*)(hr + o * 12 + 8);
                hh[0]=h0.x; hh[1]=h0.y; hh[2]=h0.z; hh[3]=h0.w;
                hh[4]=h1.x; hh[5]=h1.y; hh[6]=h1.z; hh[7]=h1.w;
                hh[8]=h2.x; hh[9]=h2.y; hh[10]=h2.z; hh[11]=h2.w;
            }
            float zz[4] = { z4.x, z4.y, z4.z, z4.w };

            float r0 = br, r1 = 0.f, u0 = bu, u1 = 0.f;
            float n0 = bhn, n1 = 0.f, x0 = bxn, x1 = 0.f;
            #pragma unroll
            for (int k = 0; k < 12; k += 2) {
                r0 += whr[k] * hh[k];  r1 += whr[k+1] * hh[k+1];
                u0 += whu[k] * hh[k];  u1 += whu[k+1] * hh[k+1];
                n0 += whn[k] * hh[k];  n1 += whn[k+1] * hh[k+1];
            }
            #pragma unroll
            for (int m = 0; m < 4; m += 2) {
                r0 += wir[m] * zz[m];  r1 += wir[m+1] * zz[m+1];
                u0 += wiu[m] * zz[m];  u1 += wiu[m+1] * zz[m+1];
                x0 += win[m] * zz[m];  x1 += win[m+1] * zz[m+1];
            }
            float sR = r0 + r1, sU = u0 + u1, sHN = n0 + n1, sXN = x0 + x1;

            sR  += __shfl_xor(sR, 1);  sU  += __shfl_xor(sU, 1);
            sHN += __shfl_xor(sHN, 1); sXN += __shfl_xor(sXN, 1);
            sR  += __shfl_xor(sR, 2);  sU  += __shfl_xor(sU, 2);
            sHN += __shfl_xor(sHN, 2); sXN += __shfl_xor(sXN, 2);
            sR  += __shfl_xor(sR, 4);  sU  += __shfl_xor(sU, 4);
            sHN += __shfl_xor(sHN, 4); sXN += __shfl_xor(sXN, 4);

            float r = sigm(sR);
            float u = sigm(sU);
            float n = tanh_fast(sXN + r * sHN);
            float hold = hr[j];                 // broadcast read
            float hnew = u * (hold - n) + n;    // (1-u)*n + u*h
            if (o == 0) hw[j] = hnew;
            __syncthreads();                    // the ONLY barrier per step
        }
    }

    // ---- fused head: zn = Whead @ h + bhead ; y = zn @ Wmix ----
    // final h lives in shp[TT & 1] == shp[0]
    if (tid < MIXD) {
        const float* h = shp[0];
        float a0 = 0.f, a1 = 0.f, a2 = 0.f, a3 = 0.f;
        #pragma unroll
        for (int kc = 0; kc < HID / 4; ++kc) {
            float4 wv = *(const float4*)(Whead + (size_t)tid * HID + kc * 4);
            float4 hv = *(const float4*)(h + kc * 4);
            a0 += wv.x * hv.x; a1 += wv.y * hv.y;
            a2 += wv.z * hv.z; a3 += wv.w * hv.w;
        }
        szn[tid] = bhead[tid] + ((a0 + a1) + (a2 + a3));
    }
    __syncthreads();
    if (tid < IDIM) {
        float acc = 0.f;
        #pragma unroll
        for (int m = 0; m < MIXD; ++m)
            acc += szn[m] * Wmix[(size_t)m * IDIM + tid];
        y[(size_t)b * IDIM + tid] = acc;
    }
}

extern "C" void kernel_launch(void* const* d_in, const int* in_sizes, int n_in,
                              void* d_out, int out_size, void* d_ws, size_t ws_size,
                              hipStream_t stream) {
    const float* x     = (const float*)d_in[0];
    const float* Wmix  = (const float*)d_in[1];
    const float* Wih   = (const float*)d_in[2];
    const float* Whh   = (const float*)d_in[3];
    const float* bih   = (const float*)d_in[4];
    const float* bhh   = (const float*)d_in[5];
    const float* Whead = (const float*)d_in[6];
    const float* bhead = (const float*)d_in[7];
    float* out = (float*)d_out;

    float* z = (float*)d_ws;   // [B*T, 32] = 16.78 MB

    k_mix <<<512, 256, 0, stream>>>(x, Wmix, z);
    k_scan<<<BB,  768, 0, stream>>>(z, Wih, Whh, bih, bhh, Whead, bhead, Wmix, out);
}

// Round 4
// 477.414 us; speedup vs baseline: 2.0574x; 1.1449x over previous
//
#include <hip/hip_runtime.h>

#define IDIM 512
#define MIXD 32
#define HID 96
#define BB 256
#define TT 512

__device__ __forceinline__ float sigm(float x) {
    return __builtin_amdgcn_rcpf(1.f + __expf(-x));
}
__device__ __forceinline__ float tanh_fast(float x) {
    // 1 - 2/(1+e^{2x}); saturates correctly at +-1 for large |x|
    return 1.f - 2.f * __builtin_amdgcn_rcpf(1.f + __expf(2.f * x));
}

// DPP row_shl:N add: lane i += lane (i+N) within each 16-lane row,
// out-of-row source lanes contribute 0 (bound_ctrl). Pure VALU — does NOT
// touch the shared LDS pipe (unlike __shfl_xor -> ds_swizzle).
// dpp_ctrl must be an ICE at the builtin call site -> template parameter.
template <int CTRL>
__device__ __forceinline__ float dpp_shl_add(float x) {
    int m = __builtin_amdgcn_update_dpp(0, __float_as_int(x), CTRL, 0xf, 0xf, true);
    return x + __int_as_float(m);
}
// Reduce 8 consecutive lanes (octet) into the octet's lane 0.
// shl:4 then shl:2 then shl:1 — lane0 = sum(l0..l7); upper-lane garbage unused.
__device__ __forceinline__ float octet_reduce_lane0(float x) {
    x = dpp_shl_add<0x104>(x);   // row_shl:4
    x = dpp_shl_add<0x102>(x);   // row_shl:2
    x = dpp_shl_add<0x101>(x);   // row_shl:1
    return x;
}

// ---------------- K1: z = x @ W_mix^T  (memory-bound, 268 MB read) ----------
__global__ __launch_bounds__(256) void k_mix(const float* __restrict__ x,
                                             const float* __restrict__ Wmix,
                                             float* __restrict__ z) {
    long row = (long)blockIdx.x * 256 + threadIdx.x;   // 131072 rows
    const float* xr = x + row * IDIM;
    float acc[MIXD];
    #pragma unroll
    for (int m = 0; m < MIXD; ++m) acc[m] = 0.f;
    for (int kc = 0; kc < IDIM / 4; ++kc) {
        float4 a = *(const float4*)(xr + kc * 4);
        #pragma unroll
        for (int m = 0; m < MIXD; ++m) {
            float4 w = *(const float4*)(Wmix + m * IDIM + kc * 4); // uniform -> s_load
            acc[m] += a.x * w.x + a.y * w.y + a.z * w.z + a.w * w.w;
        }
    }
    float* zr = z + row * MIXD;
    #pragma unroll
    for (int mc = 0; mc < MIXD / 4; ++mc) {
        float4 o;
        o.x = acc[mc*4+0]; o.y = acc[mc*4+1]; o.z = acc[mc*4+2]; o.w = acc[mc*4+3];
        *(float4*)(zr + mc * 4) = o;
    }
}

// ---------------- K2: GRU scan + head, 1 batch element per block ------------
// 768 threads = 12 waves (3/SIMD). h-index j = tid>>3, octet lane o = tid&7.
// Each octet computes all three gates for its j with an 8-way k-split
// (12 hh-MACs + 4 ih-MACs per gate per lane), reduced to lane 0 via DPP
// (VALU pipe). LDS per step: 4 ds_read_b128 + 1 ds_read_b32 + 1 write per
// wave, ONE barrier per step, ZERO global ops in the loop.
__global__ __launch_bounds__(768) void k_scan(const float* __restrict__ z,
                                              const float* __restrict__ Wih,
                                              const float* __restrict__ Whh,
                                              const float* __restrict__ bih,
                                              const float* __restrict__ bhh,
                                              const float* __restrict__ Whead,
                                              const float* __restrict__ bhead,
                                              const float* __restrict__ Wmix,
                                              float* __restrict__ y) {
    const int b   = blockIdx.x;
    const int tid = threadIdx.x;
    const int j   = tid >> 3;     // 0..95
    const int o   = tid & 7;      // 0..7

    __shared__ __align__(16) float sz[256 * MIXD];   // 32 KB: half of the z row
    __shared__ __align__(16) float shp[2][HID];      // h ping-pong
    __shared__ __align__(16) float szn[MIXD];

    // ---- weights into registers (k-slice of rows j, j+96, j+192) ----
    float whr[12], whu[12], whn[12];
    #pragma unroll
    for (int c = 0; c < 3; ++c) {
        float4 v = *(const float4*)(Whh + (size_t)(j        ) * HID + o * 12 + c * 4);
        whr[c*4+0]=v.x; whr[c*4+1]=v.y; whr[c*4+2]=v.z; whr[c*4+3]=v.w;
    }
    #pragma unroll
    for (int c = 0; c < 3; ++c) {
        float4 v = *(const float4*)(Whh + (size_t)(j +   HID) * HID + o * 12 + c * 4);
        whu[c*4+0]=v.x; whu[c*4+1]=v.y; whu[c*4+2]=v.z; whu[c*4+3]=v.w;
    }
    #pragma unroll
    for (int c = 0; c < 3; ++c) {
        float4 v = *(const float4*)(Whh + (size_t)(j + 2*HID) * HID + o * 12 + c * 4);
        whn[c*4+0]=v.x; whn[c*4+1]=v.y; whn[c*4+2]=v.z; whn[c*4+3]=v.w;
    }
    float wir[4], wiu[4], win[4];
    {
        float4 v = *(const float4*)(Wih + (size_t)(j        ) * MIXD + o * 4);
        wir[0]=v.x; wir[1]=v.y; wir[2]=v.z; wir[3]=v.w;
    }
    {
        float4 v = *(const float4*)(Wih + (size_t)(j +   HID) * MIXD + o * 4);
        wiu[0]=v.x; wiu[1]=v.y; wiu[2]=v.z; wiu[3]=v.w;
    }
    {
        float4 v = *(const float4*)(Wih + (size_t)(j + 2*HID) * MIXD + o * 4);
        win[0]=v.x; win[1]=v.y; win[2]=v.z; win[3]=v.w;
    }
    float br = 0.f, bu = 0.f, bxn = 0.f, bhn = 0.f;
    if (o == 0) {
        br  = bih[j]       + bhh[j];
        bu  = bih[j + HID] + bhh[j + HID];
        bxn = bih[j + 2*HID];
        bhn = bhh[j + 2*HID];
    }

    if (tid < HID) shp[0][tid] = 0.f;   // h0 = 0 (covered by stage barrier)

    const float4* zb4 = (const float4*)(z + (size_t)b * TT * MIXD);
    float4* sz4 = (float4*)sz;

    for (int c = 0; c < TT / 256; ++c) {
        // stage 256 steps of z (2048 float4); prior step's barrier makes
        // overwrite safe, next barrier makes it visible
        for (int idx = tid; idx < 2048; idx += 768)
            sz4[idx] = zb4[c * 2048 + idx];
        __syncthreads();

        for (int tt = 0; tt < 256; ++tt) {
            const int t = (c << 8) + tt;
            const float* hr = shp[t & 1];
            float*       hw = shp[(t + 1) & 1];
            const float* zrow = sz + tt * MIXD;

            float4 z4 = *(const float4*)(zrow + o * 4);
            float hh[12];
            {
                float4 h0 = *(const float4*)(hr + o * 12);
                float4 h1 = *(const float4*)(hr + o * 12 + 4);
                float4 h2 = *(const float4*)(hr + o * 12 + 8);
                hh[0]=h0.x; hh[1]=h0.y; hh[2]=h0.z; hh[3]=h0.w;
                hh[4]=h1.x; hh[5]=h1.y; hh[6]=h1.z; hh[7]=h1.w;
                hh[8]=h2.x; hh[9]=h2.y; hh[10]=h2.z; hh[11]=h2.w;
            }
            float zz[4] = { z4.x, z4.y, z4.z, z4.w };

            float r0 = br, r1 = 0.f, u0 = bu, u1 = 0.f;
            float n0 = bhn, n1 = 0.f, x0 = bxn, x1 = 0.f;
            #pragma unroll
            for (int k = 0; k < 12; k += 2) {
                r0 += whr[k] * hh[k];  r1 += whr[k+1] * hh[k+1];
                u0 += whu[k] * hh[k];  u1 += whu[k+1] * hh[k+1];
                n0 += whn[k] * hh[k];  n1 += whn[k+1] * hh[k+1];
            }
            #pragma unroll
            for (int m = 0; m < 4; m += 2) {
                r0 += wir[m] * zz[m];  r1 += wir[m+1] * zz[m+1];
                u0 += wiu[m] * zz[m];  u1 += wiu[m+1] * zz[m+1];
                x0 += win[m] * zz[m];  x1 += win[m+1] * zz[m+1];
            }
            // Octet reduce on the VALU pipe (DPP), result lands in lane o==0.
            float sR  = octet_reduce_lane0(r0 + r1);
            float sU  = octet_reduce_lane0(u0 + u1);
            float sHN = octet_reduce_lane0(n0 + n1);
            float sXN = octet_reduce_lane0(x0 + x1);

            float r = sigm(sR);
            float u = sigm(sU);
            float n = tanh_fast(sXN + r * sHN);
            float hold = hr[j];                 // broadcast read (b32)
            float hnew = u * (hold - n) + n;    // (1-u)*n + u*h
            if (o == 0) hw[j] = hnew;
            __syncthreads();                    // the ONLY barrier per step
        }
    }

    // ---- fused head: zn = Whead @ h + bhead ; y = zn @ Wmix ----
    // final h lives in shp[TT & 1] == shp[0]
    if (tid < MIXD) {
        const float* h = shp[0];
        float a0 = 0.f, a1 = 0.f, a2 = 0.f, a3 = 0.f;
        #pragma unroll
        for (int kc = 0; kc < HID / 4; ++kc) {
            float4 wv = *(const float4*)(Whead + (size_t)tid * HID + kc * 4);
            float4 hv = *(const float4*)(h + kc * 4);
            a0 += wv.x * hv.x; a1 += wv.y * hv.y;
            a2 += wv.z * hv.z; a3 += wv.w * hv.w;
        }
        szn[tid] = bhead[tid] + ((a0 + a1) + (a2 + a3));
    }
    __syncthreads();
    if (tid < IDIM) {
        float acc = 0.f;
        #pragma unroll
        for (int m = 0; m < MIXD; ++m)
            acc += szn[m] * Wmix[(size_t)m * IDIM + tid];
        y[(size_t)b * IDIM + tid] = acc;
    }
}

extern "C" void kernel_launch(void* const* d_in, const int* in_sizes, int n_in,
                              void* d_out, int out_size, void* d_ws, size_t ws_size,
                              hipStream_t stream) {
    const float* x     = (const float*)d_in[0];
    const float* Wmix  = (const float*)d_in[1];
    const float* Wih   = (const float*)d_in[2];
    const float* Whh   = (const float*)d_in[3];
    const float* bih   = (const float*)d_in[4];
    const float* bhh   = (const float*)d_in[5];
    const float* Whead = (const float*)d_in[6];
    const float* bhead = (const float*)d_in[7];
    float* out = (float*)d_out;

    float* z = (float*)d_ws;   // [B*T, 32] = 16.78 MB

    k_mix <<<512, 256, 0, stream>>>(x, Wmix, z);
    k_scan<<<BB,  768, 0, stream>>>(z, Wih, Whh, bih, bhh, Whead, bhead, Wmix, out);
}